// Round 1
// baseline (240.105 us; speedup 1.0000x reference)
//
#include <hip/hip_runtime.h>
#include <math.h>

#define BB 2
#define VV 768
#define HID 128
#define NH 8
#define HD 16

// ---------------------------------------------------------------------------
// Kernel 1: edge_mask[b][q][j] = mean(edge_gate[b][q][j][:])   (128-wide rows)
// float4 per lane: 64 lanes x 16B = 1KB = 2 rows per wave-instruction.
// Lanes 0..31 cover row 2p, lanes 32..63 cover row 2p+1; half-wave reduce.
// ---------------------------------------------------------------------------
__global__ __launch_bounds__(256) void edge_mean_kernel(
    const float* __restrict__ eg, float* __restrict__ mask) {
    const int lane = threadIdx.x & 63;
    const long long NPAIR = (long long)BB * VV * VV / 2;  // 589824 row-pairs
    long long w  = (long long)blockIdx.x * (blockDim.x >> 6) + (threadIdx.x >> 6);
    long long nw = (long long)gridDim.x * (blockDim.x >> 6);
    for (long long p = w; p < NPAIR; p += nw) {
        float4 v = ((const float4*)eg)[p * 64 + lane];
        float s = v.x + v.y + v.z + v.w;
        s += __shfl_xor(s, 1);
        s += __shfl_xor(s, 2);
        s += __shfl_xor(s, 4);
        s += __shfl_xor(s, 8);
        s += __shfl_xor(s, 16);
        if ((lane & 31) == 0)
            mask[p * 2 + (lane >> 5)] = s * (1.0f / 128.0f);
    }
}

// ---------------------------------------------------------------------------
// Kernel 2: q/k/v = x @ W^T + b, written head-major: idx = ((b*NH+h)*VV+v)*HD+d
// One 128-thread block per (b,v) row; x row staged in LDS.
// ---------------------------------------------------------------------------
__global__ __launch_bounds__(128) void qkv_kernel(
    const float* __restrict__ x,
    const float* __restrict__ Wq, const float* __restrict__ bq,
    const float* __restrict__ Wk, const float* __restrict__ bk,
    const float* __restrict__ Wv, const float* __restrict__ bv,
    float* __restrict__ qh, float* __restrict__ kh, float* __restrict__ vh) {
    const int row = blockIdx.x;      // b*VV + v
    const int c   = threadIdx.x;     // output column = h*HD + d
    __shared__ float xs[HID];
    xs[c] = x[row * HID + c];
    __syncthreads();
    const float4* xs4 = (const float4*)xs;
    const float4* wq4 = (const float4*)(Wq + c * HID);
    const float4* wk4 = (const float4*)(Wk + c * HID);
    const float4* wv4 = (const float4*)(Wv + c * HID);
    float aq = 0.f, ak = 0.f, av = 0.f;
#pragma unroll
    for (int k4 = 0; k4 < HID / 4; ++k4) {
        float4 xv = xs4[k4];
        float4 a = wq4[k4];
        aq += xv.x * a.x + xv.y * a.y + xv.z * a.z + xv.w * a.w;
        float4 bqv = wk4[k4];
        ak += xv.x * bqv.x + xv.y * bqv.y + xv.z * bqv.z + xv.w * bqv.w;
        float4 cv = wv4[k4];
        av += xv.x * cv.x + xv.y * cv.y + xv.z * cv.z + xv.w * cv.w;
    }
    const int b = row / VV, vi = row - b * VV;
    const int idx = ((b * NH + (c >> 4)) * VV + vi) * HD + (c & 15);
    qh[idx] = aq + bq[c];
    kh[idx] = ak + bk[c];
    vh[idx] = av + bv[c];
}

// ---------------------------------------------------------------------------
// Kernel 3: attention. One wave per (b,h,q): scores -> LDS, wave-max,
// exp/sum fused with P*V accumulation, butterfly reduce of acc[16].
// Block = 4 waves; q fastest in wave-id so consecutive blocks share (b,h)
// (L2/L1 locality for k/v slices, 48KB each).
// ---------------------------------------------------------------------------
__global__ __launch_bounds__(256) void attn_kernel(
    const float* __restrict__ qh, const float* __restrict__ kh,
    const float* __restrict__ vh, const float* __restrict__ mask,
    float* __restrict__ att) {
    __shared__ float sc[4][VV];
    const int wid  = threadIdx.x >> 6;
    const int lane = threadIdx.x & 63;
    const int gw   = blockIdx.x * 4 + wid;   // ((b*NH+h)*VV + qi)
    const int qi   = gw % VV;
    const int bh   = gw / VV;
    const int b    = bh >> 3, h = bh & 7;

    // q vector (16 floats) broadcast-loaded into registers
    const float4* qp = (const float4*)(qh + (size_t)(bh * VV + qi) * HD);
    const float4 q0 = qp[0], q1 = qp[1], q2 = qp[2], q3 = qp[3];

    const float* mrow = mask + (size_t)(b * VV + qi) * VV;
    const float* kbase = kh + (size_t)bh * VV * HD;
    const float* vbase = vh + (size_t)bh * VV * HD;

    // pass 1: scores + max
    float m = -INFINITY;
#pragma unroll
    for (int t = 0; t < VV / 64; ++t) {
        const int j = lane + 64 * t;
        const float4* kp = (const float4*)(kbase + j * HD);
        float4 k0 = kp[0], k1 = kp[1], k2 = kp[2], k3 = kp[3];
        float dot = q0.x * k0.x + q0.y * k0.y + q0.z * k0.z + q0.w * k0.w
                  + q1.x * k1.x + q1.y * k1.y + q1.z * k1.z + q1.w * k1.w
                  + q2.x * k2.x + q2.y * k2.y + q2.z * k2.z + q2.w * k2.w
                  + q3.x * k3.x + q3.y * k3.y + q3.z * k3.z + q3.w * k3.w;
        float s = dot * 0.25f * mrow[j];
        sc[wid][j] = s;
        m = fmaxf(m, s);
    }
#pragma unroll
    for (int off = 1; off < 64; off <<= 1) m = fmaxf(m, __shfl_xor(m, off));

    // pass 2: exp, sum, P*V accumulate
    float sum = 0.f;
    float acc[HD];
#pragma unroll
    for (int d = 0; d < HD; ++d) acc[d] = 0.f;
#pragma unroll
    for (int t = 0; t < VV / 64; ++t) {
        const int j = lane + 64 * t;
        float e = __expf(sc[wid][j] - m);
        sum += e;
        const float4* vp = (const float4*)(vbase + j * HD);
        float4 v0 = vp[0], v1 = vp[1], v2 = vp[2], v3 = vp[3];
        acc[0]  += e * v0.x; acc[1]  += e * v0.y; acc[2]  += e * v0.z; acc[3]  += e * v0.w;
        acc[4]  += e * v1.x; acc[5]  += e * v1.y; acc[6]  += e * v1.z; acc[7]  += e * v1.w;
        acc[8]  += e * v2.x; acc[9]  += e * v2.y; acc[10] += e * v2.z; acc[11] += e * v2.w;
        acc[12] += e * v3.x; acc[13] += e * v3.y; acc[14] += e * v3.z; acc[15] += e * v3.w;
    }
#pragma unroll
    for (int off = 1; off < 64; off <<= 1) {
        sum += __shfl_xor(sum, off);
#pragma unroll
        for (int d = 0; d < HD; ++d) acc[d] += __shfl_xor(acc[d], off);
    }

    const float inv = 1.0f / sum;
    float outv = 0.f;
#pragma unroll
    for (int d = 0; d < HD; ++d)
        if (lane == d) outv = acc[d];
    if (lane < HD)
        att[(size_t)(b * VV + qi) * HID + h * HD + lane] = outv * inv;
}

// ---------------------------------------------------------------------------
// Kernel 4: out = att @ Wo^T + bo
// ---------------------------------------------------------------------------
__global__ __launch_bounds__(128) void outproj_kernel(
    const float* __restrict__ att, const float* __restrict__ Wo,
    const float* __restrict__ bo, float* __restrict__ out) {
    const int row = blockIdx.x;
    const int c   = threadIdx.x;
    __shared__ float xs[HID];
    xs[c] = att[row * HID + c];
    __syncthreads();
    const float4* xs4 = (const float4*)xs;
    const float4* wo4 = (const float4*)(Wo + c * HID);
    float a = 0.f;
#pragma unroll
    for (int k4 = 0; k4 < HID / 4; ++k4) {
        float4 xv = xs4[k4];
        float4 wv = wo4[k4];
        a += xv.x * wv.x + xv.y * wv.y + xv.z * wv.z + xv.w * wv.w;
    }
    out[row * HID + c] = a + bo[c];
}

extern "C" void kernel_launch(void* const* d_in, const int* in_sizes, int n_in,
                              void* d_out, int out_size, void* d_ws, size_t ws_size,
                              hipStream_t stream) {
    const float* x  = (const float*)d_in[0];
    const float* eg = (const float*)d_in[1];
    const float* Wq = (const float*)d_in[2];
    const float* bq = (const float*)d_in[3];
    const float* Wk = (const float*)d_in[4];
    const float* bk = (const float*)d_in[5];
    const float* Wv = (const float*)d_in[6];
    const float* bv = (const float*)d_in[7];
    const float* Wo = (const float*)d_in[8];
    const float* bo = (const float*)d_in[9];
    float* out = (float*)d_out;

    float* ws   = (float*)d_ws;
    float* mask = ws;                                        // B*V*V
    float* qh   = mask + (size_t)BB * VV * VV;               // B*V*HID each
    float* kh   = qh + (size_t)BB * VV * HID;
    float* vh   = kh + (size_t)BB * VV * HID;
    float* att  = vh + (size_t)BB * VV * HID;

    hipLaunchKernelGGL(edge_mean_kernel, dim3(2048), dim3(256), 0, stream, eg, mask);
    hipLaunchKernelGGL(qkv_kernel, dim3(BB * VV), dim3(128), 0, stream,
                       x, Wq, bq, Wk, bk, Wv, bv, qh, kh, vh);
    hipLaunchKernelGGL(attn_kernel, dim3(BB * NH * VV / 4), dim3(256), 0, stream,
                       qh, kh, vh, mask, att);
    hipLaunchKernelGGL(outproj_kernel, dim3(BB * VV), dim3(128), 0, stream,
                       att, Wo, bo, out);
}